// Round 12
// baseline (40.247 us; speedup 1.0000x reference)
//
#include <hip/hip_runtime.h>
#include <hip/hip_bf16.h>
#include <stdint.h>

// Quanvolution + linear(784->10) + log_softmax via MFMA, B=65536, fp32 in/out.
// R11: 8-way K-split at <=64 VGPR to unlock 8 waves/SIMD (m69: occupancy
// steps at VGPR 64/128/256). 2048 blocks x 512 thr (8 waves, one K-octant
// each); per wave ONE hoisted 3-kt load window (kq0: two 2-kt windows so the
// static VGPR max stays at the 3-kt shape). Merge 8 partial accumulators via
// 7KB LDS, 1 barrier, wave 0 does the epilogue.
// K-slot map (validated R9/R10): K-block kt covers row bytes [128kt,128kt+128);
// lane (r16,kg) loads float4 at +16kg and +64+16kg; every even float pair
// (j,j+1) is a top/bottom pair of one patch; pads (jp>=784) have W=0;
// kt=24 second quad clamps to row start (W=0 annihilates).

typedef __attribute__((ext_vector_type(8))) short short8;
typedef __attribute__((ext_vector_type(4))) float f32x4;

// ---- pre-kernel: bake W -> bf16 frags ws[kt][lane][e], 25 KB ----
__global__ void quanv_wprep_kernel(const float* __restrict__ Wm,
                                   uint32_t* __restrict__ ws) {
    const int idx = blockIdx.x * 256 + threadIdx.x;   // [0, 6400)
    if (idx >= 6400) return;
    const int kt  = idx >> 8;       // 0..24
    const int rem = idx & 255;
    const int l   = rem >> 2;       // lane 0..63
    const int d   = rem & 3;        // u32 -> e = 2d, 2d+1
    const int n   = l & 15;
    const int kg  = l >> 4;
    uint32_t outv = 0;
    if (n < 10) {
        uint32_t hv[2];
#pragma unroll
        for (int d2 = 0; d2 < 2; ++d2) {
            const int e  = 2 * d + d2;
            const int jp = 32 * kt + 4 * kg + 16 * (e >> 2) + 2 * ((e >> 1) & 1);
            float v = 0.f;
            if (jp < 784) {
                const int ri = jp / 28;          // image row
                const int pc = (jp % 28) >> 1;   // patch col
                const int pr = ri >> 1;          // patch row
                const int ho = ri & 1;           // 0=top pair, 1=bottom pair
                const int col = (pr * 14 + pc) * 4 + 2 * ho + (e & 1);
                v = Wm[n * 784 + col];
            }
            hv[d2] = (uint32_t)__bfloat16_as_ushort(__float2bfloat16(v));
        }
        outv = hv[0] | (hv[1] << 16);
    }
    ws[idx] = outv;
}

// ---- 8 features from two float4s (pairs (x,y),(z,w) each) ----
#define FEAT8(VA, VB, A) do {                                                 \
    { const float ce=__cosf((VA).x), co=__cosf((VA).y);                       \
      (A)[0]=(short)__bfloat16_as_ushort(__float2bfloat16(ce + (VA).x));      \
      (A)[1]=(short)__bfloat16_as_ushort(__float2bfloat16(fmaf(ce,co,(VA).y)));}\
    { const float ce=__cosf((VA).z), co=__cosf((VA).w);                       \
      (A)[2]=(short)__bfloat16_as_ushort(__float2bfloat16(ce + (VA).z));      \
      (A)[3]=(short)__bfloat16_as_ushort(__float2bfloat16(fmaf(ce,co,(VA).w)));}\
    { const float ce=__cosf((VB).x), co=__cosf((VB).y);                       \
      (A)[4]=(short)__bfloat16_as_ushort(__float2bfloat16(ce + (VB).x));      \
      (A)[5]=(short)__bfloat16_as_ushort(__float2bfloat16(fmaf(ce,co,(VB).y)));}\
    { const float ce=__cosf((VB).z), co=__cosf((VB).w);                       \
      (A)[6]=(short)__bfloat16_as_ushort(__float2bfloat16(ce + (VB).z));      \
      (A)[7]=(short)__bfloat16_as_ushort(__float2bfloat16(fmaf(ce,co,(VB).w)));}\
} while (0)

// ---- one K-window: issue ALL loads, then compute (full static unroll) ----
template <int KT0, int N>
__device__ __forceinline__ void quarter(const float* __restrict__ px,
                                        const char* __restrict__ wsb,
                                        int l, f32x4& acc) {
    float4 va[N], vb[N];
    short8 wf[N];
    const char* wbp = wsb + KT0 * 1024 + l * 16;
#pragma unroll
    for (int j = 0; j < N; ++j) {
        const int kt = KT0 + j;
        va[j] = *(const float4*)(px + 32 * kt);
        // kt=24 second quad would cross the row end -> clamp (W=0 kills it)
        vb[j] = (kt == 24) ? *(const float4*)(px)
                           : *(const float4*)(px + 32 * kt + 16);
        wf[j] = *(const short8*)(wbp + j * 1024);
    }
#pragma unroll
    for (int j = 0; j < N; ++j) {
        short8 a;
        FEAT8(va[j], vb[j], a);
        acc = __builtin_amdgcn_mfma_f32_16x16x32_bf16(a, wf[j], acc, 0, 0, 0);
    }
}

__global__ __launch_bounds__(512, 8)
void quanv_mfma7_kernel(const float* __restrict__ x,
                        const char* __restrict__ wsb,   // bf16 frags [25][64][8]
                        const float* __restrict__ bias,
                        float* __restrict__ out) {
    __shared__ f32x4 red[7][64];   // 7 KB: kq=1..7 accumulators

    const int t   = threadIdx.x;
    const int l   = t & 63;
    const int kq  = __builtin_amdgcn_readfirstlane(t >> 6);   // K-octant 0..7
    const int r16 = l & 15;
    const int kg  = l >> 4;
    const int rowBase = blockIdx.x * 16;
    const float* px = x + (size_t)(rowBase + r16) * 784 + 4 * kg;

    f32x4 acc = {0.f, 0.f, 0.f, 0.f};

    // kq0: kt 0-3 as two 2-kt windows (keeps static VGPR max at 3-kt shape)
    if      (kq == 0) { quarter<0, 2>(px, wsb, l, acc);
                        quarter<2, 2>(px, wsb, l, acc); }
    else if (kq == 1) quarter<4,  3>(px, wsb, l, acc);
    else if (kq == 2) quarter<7,  3>(px, wsb, l, acc);
    else if (kq == 3) quarter<10, 3>(px, wsb, l, acc);
    else if (kq == 4) quarter<13, 3>(px, wsb, l, acc);
    else if (kq == 5) quarter<16, 3>(px, wsb, l, acc);
    else if (kq == 6) quarter<19, 3>(px, wsb, l, acc);
    else              quarter<22, 3>(px, wsb, l, acc);

    // ---- merge K-octants via LDS ----
    if (kq != 0) red[kq - 1][l] = acc;
    __syncthreads();
    if (kq == 0) {
#pragma unroll
        for (int s = 0; s < 7; ++s) {
            const f32x4 o = red[s][l];
#pragma unroll
            for (int j = 0; j < 4; ++j) acc[j] += o[j];
        }

        // ---- epilogue: lane holds D[m=4*kg+j][n=r16]; log_softmax over n ----
        const float bn = bias[r16 < 10 ? r16 : 0];
#pragma unroll
        for (int j = 0; j < 4; ++j) {
            float v = (r16 < 10) ? (acc[j] + bn) : -1e30f;
            float mx = v;
            mx = fmaxf(mx, __shfl_xor(mx, 1, 64));
            mx = fmaxf(mx, __shfl_xor(mx, 2, 64));
            mx = fmaxf(mx, __shfl_xor(mx, 4, 64));
            mx = fmaxf(mx, __shfl_xor(mx, 8, 64));
            float e = (r16 < 10) ? __expf(v - mx) : 0.f;
            float s = e;
            s += __shfl_xor(s, 1, 64);
            s += __shfl_xor(s, 2, 64);
            s += __shfl_xor(s, 4, 64);
            s += __shfl_xor(s, 8, 64);
            const float ls = __logf(s) + mx;
            if (r16 < 10)
                out[(size_t)(rowBase + 4 * kg + j) * 10 + r16] = v - ls;
        }
    }
}

extern "C" void kernel_launch(void* const* d_in, const int* in_sizes, int n_in,
                              void* d_out, int out_size, void* d_ws, size_t ws_size,
                              hipStream_t stream) {
    const float* x    = (const float*)d_in[0];   // [65536, 784]
    const float* Wm   = (const float*)d_in[1];   // [10, 784]
    const float* bias = (const float*)d_in[2];   // [10]
    float* out        = (float*)d_out;           // [65536, 10]

    quanv_wprep_kernel<<<dim3(25), dim3(256), 0, stream>>>(
        Wm, (uint32_t*)d_ws);
    quanv_mfma7_kernel<<<dim3(4096), dim3(512), 0, stream>>>(
        x, (const char*)d_ws, bias, out);
}